// Round 1
// baseline (711.820 us; speedup 1.0000x reference)
//
#include <hip/hip_runtime.h>

// GraphNetworkLayer: B=8, N=4096, E=16384, G=64, D=128, all fp32.
// Round 0: correctness-first fp32 VALU implementation.
//  - edge kernel: relu(concat[edges,sent,recv,glob] @ We + be); fused residual
//    write of edges_out; atomic scatter into adjacent_edges (by receiver) and
//    edge_agg (by edge_graph_idx).
//  - node kernel: relu(concat[nodes,adjacent,glob] @ Wn + bn); fused residual
//    nodes_out; atomic scatter into node_agg.
//  - global kernel: relu(concat[node_agg,edge_agg,glob] @ Wg + bg) + residual.
//  - idx passthrough written as FLOAT VALUES (out buffer is read as float32).

#define DD 128
constexpr int B_ = 8, N_ = 4096, E_ = 16384, G_ = 64;
constexpr int NODES_SZ = B_ * N_ * DD;   // 4,194,304
constexpr int EDGES_SZ = B_ * E_ * DD;   // 16,777,216
constexpr int BE_ = B_ * E_;             // 131,072
constexpr int BN_ = B_ * N_;             // 32,768
constexpr int BG_ = B_ * G_;             // 512
constexpr int GLOB_SZ = BG_ * DD;        // 65,536

// d_out offsets (float elements), reference tuple return order
constexpr int OFF_NODES = 0;
constexpr int OFF_EDGES = OFF_NODES + NODES_SZ;  // 4,194,304
constexpr int OFF_RECV  = OFF_EDGES + EDGES_SZ;  // 20,971,520
constexpr int OFF_SEND  = OFF_RECV + BE_;        // 21,102,592
constexpr int OFF_GLOB  = OFF_SEND + BE_;        // 21,233,664
constexpr int OFF_NGI   = OFF_GLOB + GLOB_SZ;    // 21,299,200
constexpr int OFF_EGI   = OFF_NGI + BN_;         // 21,331,968

// workspace offsets (float elements)
constexpr int WS_ADJ   = 0;                       // [B,N,D] adjacent_edges
constexpr int WS_EAGG  = NODES_SZ;                // [B,G,D] edge_agg
constexpr int WS_NAGG  = NODES_SZ + GLOB_SZ;      // [B,G,D] node_agg
constexpr int WS_TOTAL = NODES_SZ + 2 * GLOB_SZ;  // 4,325,376 floats (17.3 MB)

__global__ __launch_bounds__(256) void zero_ws(float4* ws, int n4) {
    int i = blockIdx.x * blockDim.x + threadIdx.x;
    int stride = gridDim.x * blockDim.x;
    float4 z = {0.f, 0.f, 0.f, 0.f};
    for (; i < n4; i += stride) ws[i] = z;
}

__global__ __launch_bounds__(256) void copy_idx(
    const int* __restrict__ recv, const int* __restrict__ send,
    const int* __restrict__ ngi, const int* __restrict__ egi,
    float* __restrict__ out) {
    int i = blockIdx.x * blockDim.x + threadIdx.x;
    int stride = gridDim.x * blockDim.x;
    const int total = 3 * BE_ + BN_;  // recv, send, ngi, egi
    for (; i < total; i += stride) {
        if (i < BE_)                 out[OFF_RECV + i] = (float)recv[i];
        else if (i < 2 * BE_)        out[OFF_SEND + (i - BE_)] = (float)send[i - BE_];
        else if (i < 2 * BE_ + BN_)  out[OFF_NGI + (i - 2 * BE_)] = (float)ngi[i - 2 * BE_];
        else                         out[OFF_EGI + (i - 2 * BE_ - BN_)] = (float)egi[i - 2 * BE_ - BN_];
    }
}

// ---------------- edge block: rows = B*E, K = 512 -----------------
// block = 256 threads, 32 rows/block, K in 2 chunks of 256.
// LDS tile transposed: a_lds[k][row], pad 36 keeps float4 reads 16B-aligned.
__global__ __launch_bounds__(256) void edge_block(
    const float* __restrict__ nodes, const float* __restrict__ edges,
    const int* __restrict__ receivers, const int* __restrict__ senders,
    const float* __restrict__ glob, const int* __restrict__ egi,
    const float* __restrict__ We, const float* __restrict__ be,
    const float* __restrict__ w_res,
    float* __restrict__ out, float* __restrict__ adj, float* __restrict__ eagg) {
    __shared__ float a_lds[256][36];  // 36 KB -> 4 blocks/CU
    const int tid = threadIdx.x;
    const int row0 = blockIdx.x * 32;
    const int r0 = (tid >> 5) << 2;   // 0..28 (4 rows/thread)
    const int c0 = (tid & 31) << 2;   // 0..124 (4 cols/thread)

    // staging mapping: 8 threads per row
    const int srow = tid >> 3;
    const int skq  = tid & 7;
    const int ge_s = row0 + srow;
    const int b_s  = ge_s >> 14;  // /E
    const float* src0 = edges + (long)ge_s * DD;                               // k 0..127
    const float* src1 = nodes + ((long)b_s * N_ + senders[ge_s]) * DD;         // 128..255
    const float* src2 = nodes + ((long)b_s * N_ + receivers[ge_s]) * DD;       // 256..383
    const float* src3 = glob  + ((long)b_s * G_ + egi[ge_s]) * DD;             // 384..511

    float acc[4][4] = {};

    // chunk order 1 then 0 so the final LDS contents include k<128 (= edges
    // values), letting the epilogue read the residual source from LDS.
    #pragma unroll
    for (int kc = 1; kc >= 0; --kc) {
        __syncthreads();
        #pragma unroll
        for (int i = 0; i < 8; ++i) {
            const int kk = (skq + i * 8) * 4;          // 0..252 within chunk
            const int kglob = kc * 256 + kk;
            const int seg = (kc * 256 + i * 32) >> 7;  // compile-time after unroll
            const float* sp = (seg == 0) ? src0 : (seg == 1) ? src1 : (seg == 2) ? src2 : src3;
            const float4 v = *(const float4*)(sp + (kglob & 127));
            a_lds[kk + 0][srow] = v.x;
            a_lds[kk + 1][srow] = v.y;
            a_lds[kk + 2][srow] = v.z;
            a_lds[kk + 3][srow] = v.w;
        }
        __syncthreads();
        const float* wp = We + kc * 256 * DD + c0;
        #pragma unroll 4
        for (int k = 0; k < 256; ++k) {
            const float4 a = *(const float4*)&a_lds[k][r0];
            const float4 w = *(const float4*)(wp + k * DD);
            const float av[4] = {a.x, a.y, a.z, a.w};
            const float wv[4] = {w.x, w.y, w.z, w.w};
            #pragma unroll
            for (int ii = 0; ii < 4; ++ii)
                #pragma unroll
                for (int jj = 0; jj < 4; ++jj)
                    acc[ii][jj] += av[ii] * wv[jj];
        }
    }

    const float wr = w_res[0];
    const float4 bv = *(const float4*)(be + c0);
    const float bva[4] = {bv.x, bv.y, bv.z, bv.w};
    #pragma unroll
    for (int i = 0; i < 4; ++i) {
        const int ge = row0 + r0 + i;
        const int b = ge >> 14;
        const int rc = receivers[ge];
        const int gg = egi[ge];
        float u[4];
        float4 ov;
        #pragma unroll
        for (int jj = 0; jj < 4; ++jj) {
            u[jj] = fmaxf(acc[i][jj] + bva[jj], 0.f);
        }
        // edges residual source from LDS chunk 0 (k = d < 128)
        ov.x = a_lds[c0 + 0][r0 + i] + wr * u[0];
        ov.y = a_lds[c0 + 1][r0 + i] + wr * u[1];
        ov.z = a_lds[c0 + 2][r0 + i] + wr * u[2];
        ov.w = a_lds[c0 + 3][r0 + i] + wr * u[3];
        *(float4*)(out + OFF_EDGES + (long)ge * DD + c0) = ov;
        float* ap = adj  + ((long)b * N_ + rc) * DD + c0;
        float* ep = eagg + ((long)b * G_ + gg) * DD + c0;
        #pragma unroll
        for (int jj = 0; jj < 4; ++jj) {
            atomicAdd(ap + jj, u[jj]);
            atomicAdd(ep + jj, u[jj]);
        }
    }
}

// ---------------- node block: rows = B*N, K = 384 -----------------
__global__ __launch_bounds__(256) void node_block(
    const float* __restrict__ nodes, const float* __restrict__ adj,
    const float* __restrict__ glob, const int* __restrict__ ngi,
    const float* __restrict__ Wn, const float* __restrict__ bn,
    const float* __restrict__ w_res,
    float* __restrict__ out, float* __restrict__ nagg) {
    __shared__ float a_lds[192][36];  // 27.6 KB -> 5 blocks/CU
    const int tid = threadIdx.x;
    const int row0 = blockIdx.x * 32;
    const int r0 = (tid >> 5) << 2;
    const int c0 = (tid & 31) << 2;

    const int srow = tid >> 3;
    const int skq  = tid & 7;
    const int gn_s = row0 + srow;
    const int b_s  = gn_s >> 12;  // /N
    const float* src0 = nodes + (long)gn_s * DD;                        // k 0..127
    const float* src1 = adj   + (long)gn_s * DD;                        // 128..255
    const float* src2 = glob  + ((long)b_s * G_ + ngi[gn_s]) * DD;      // 256..383

    float acc[4][4] = {};

    #pragma unroll
    for (int kc = 1; kc >= 0; --kc) {
        __syncthreads();
        #pragma unroll
        for (int i = 0; i < 6; ++i) {
            const int kk = (skq + i * 8) * 4;          // 0..188 within chunk
            const int kglob = kc * 192 + kk;
            const int seg = (kc * 192 + i * 32) >> 7;
            const float* sp = (seg == 0) ? src0 : (seg == 1) ? src1 : src2;
            const float4 v = *(const float4*)(sp + (kglob & 127));
            a_lds[kk + 0][srow] = v.x;
            a_lds[kk + 1][srow] = v.y;
            a_lds[kk + 2][srow] = v.z;
            a_lds[kk + 3][srow] = v.w;
        }
        __syncthreads();
        const float* wp = Wn + kc * 192 * DD + c0;
        #pragma unroll 4
        for (int k = 0; k < 192; ++k) {
            const float4 a = *(const float4*)&a_lds[k][r0];
            const float4 w = *(const float4*)(wp + k * DD);
            const float av[4] = {a.x, a.y, a.z, a.w};
            const float wv[4] = {w.x, w.y, w.z, w.w};
            #pragma unroll
            for (int ii = 0; ii < 4; ++ii)
                #pragma unroll
                for (int jj = 0; jj < 4; ++jj)
                    acc[ii][jj] += av[ii] * wv[jj];
        }
    }

    const float wr = w_res[0];
    const float4 bv = *(const float4*)(bn + c0);
    const float bva[4] = {bv.x, bv.y, bv.z, bv.w};
    #pragma unroll
    for (int i = 0; i < 4; ++i) {
        const int gn = row0 + r0 + i;
        const int b = gn >> 12;
        const int gg = ngi[gn];
        float u[4];
        float4 ov;
        #pragma unroll
        for (int jj = 0; jj < 4; ++jj) {
            u[jj] = fmaxf(acc[i][jj] + bva[jj], 0.f);
        }
        ov.x = a_lds[c0 + 0][r0 + i] + wr * u[0];
        ov.y = a_lds[c0 + 1][r0 + i] + wr * u[1];
        ov.z = a_lds[c0 + 2][r0 + i] + wr * u[2];
        ov.w = a_lds[c0 + 3][r0 + i] + wr * u[3];
        *(float4*)(out + OFF_NODES + (long)gn * DD + c0) = ov;
        float* np = nagg + ((long)b * G_ + gg) * DD + c0;
        #pragma unroll
        for (int jj = 0; jj < 4; ++jj) atomicAdd(np + jj, u[jj]);
    }
}

// ---------------- global block: rows = B*G = 512, K = 384 -----------------
__global__ __launch_bounds__(128) void global_block(
    const float* __restrict__ nagg, const float* __restrict__ eagg,
    const float* __restrict__ glob,
    const float* __restrict__ Wg, const float* __restrict__ bg,
    const float* __restrict__ w_res, float* __restrict__ out) {
    __shared__ float gin[384];
    const int row = blockIdx.x;   // 0..511
    const int tid = threadIdx.x;  // 0..127
    gin[tid]       = nagg[row * DD + tid];
    gin[128 + tid] = eagg[row * DD + tid];
    gin[256 + tid] = glob[row * DD + tid];
    __syncthreads();
    float acc = bg[tid];
    #pragma unroll 4
    for (int k = 0; k < 384; ++k) acc += gin[k] * Wg[k * DD + tid];
    const float upd = fmaxf(acc, 0.f);
    out[OFF_GLOB + row * DD + tid] = glob[row * DD + tid] + w_res[0] * upd;
}

extern "C" void kernel_launch(void* const* d_in, const int* in_sizes, int n_in,
                              void* d_out, int out_size, void* d_ws, size_t ws_size,
                              hipStream_t stream) {
    const float* nodes     = (const float*)d_in[0];
    const float* edges     = (const float*)d_in[1];
    const int*   receivers = (const int*)d_in[2];
    const int*   senders   = (const int*)d_in[3];
    const float* glob      = (const float*)d_in[4];
    const int*   ngi       = (const int*)d_in[5];
    const int*   egi       = (const int*)d_in[6];
    const float* We        = (const float*)d_in[7];
    const float* be        = (const float*)d_in[8];
    const float* Wn        = (const float*)d_in[9];
    const float* bn        = (const float*)d_in[10];
    const float* Wg        = (const float*)d_in[11];
    const float* bg        = (const float*)d_in[12];
    const float* w_res     = (const float*)d_in[13];
    float* out = (float*)d_out;
    float* ws  = (float*)d_ws;
    float* adj  = ws + WS_ADJ;
    float* eagg = ws + WS_EAGG;
    float* nagg = ws + WS_NAGG;

    hipLaunchKernelGGL(zero_ws, dim3(1024), dim3(256), 0, stream,
                       (float4*)ws, WS_TOTAL / 4);
    hipLaunchKernelGGL(copy_idx, dim3(512), dim3(256), 0, stream,
                       receivers, senders, ngi, egi, out);
    hipLaunchKernelGGL(edge_block, dim3(BE_ / 32), dim3(256), 0, stream,
                       nodes, edges, receivers, senders, glob, egi, We, be, w_res,
                       out, adj, eagg);
    hipLaunchKernelGGL(node_block, dim3(BN_ / 32), dim3(256), 0, stream,
                       nodes, adj, glob, ngi, Wn, bn, w_res, out, nagg);
    hipLaunchKernelGGL(global_block, dim3(BG_), dim3(128), 0, stream,
                       nagg, eagg, glob, Wg, bg, w_res, out);
}

// Round 2
// 683.961 us; speedup vs baseline: 1.0407x; 1.0407x over previous
//
#include <hip/hip_runtime.h>

// GraphNetworkLayer: B=8, N=4096, E=16384, G=64, D=128, fp32 in/out.
// Round 2: bf16 MFMA (16x16x32) for edge & node GEMMs.
//  - A tiles (64 rows) staged fp32->bf16 into LDS [row][k], XOR-swizzled
//    (byte ^= (row&7)<<4) to kill the stride-512B/256B bank conflict.
//  - B = weights pre-transposed to bf16 [n][k] in ws (prep kernel), read as
//    contiguous 16B frags from L1/L2.
//  - eagg/nagg: LDS [64][128] fp32 accumulate per block, then sparse flush
//    (atomic volume 67MB->16MB edge, 16MB->4MB node). adj: direct atomics.
//  - global block stays fp32 VALU (tiny).

#define DD 128
typedef unsigned short u16;
typedef __attribute__((ext_vector_type(8))) short short8;   // 8 bf16
typedef __attribute__((ext_vector_type(4))) float f32x4;

constexpr int B_ = 8, N_ = 4096, E_ = 16384, G_ = 64;
constexpr int NODES_SZ = B_ * N_ * DD;   // 4,194,304
constexpr int EDGES_SZ = B_ * E_ * DD;   // 16,777,216
constexpr int BE_ = B_ * E_;             // 131,072
constexpr int BN_ = B_ * N_;             // 32,768
constexpr int BG_ = B_ * G_;             // 512
constexpr int GLOB_SZ = BG_ * DD;        // 65,536

constexpr int OFF_NODES = 0;
constexpr int OFF_EDGES = OFF_NODES + NODES_SZ;
constexpr int OFF_RECV  = OFF_EDGES + EDGES_SZ;
constexpr int OFF_SEND  = OFF_RECV + BE_;
constexpr int OFF_GLOB  = OFF_SEND + BE_;
constexpr int OFF_NGI   = OFF_GLOB + GLOB_SZ;
constexpr int OFF_EGI   = OFF_NGI + BN_;

// workspace: fp32 accumulators, then bf16 transposed weights
constexpr int WS_ADJ   = 0;                       // [B,N,D]
constexpr int WS_EAGG  = NODES_SZ;                // [B,G,D]
constexpr int WS_NAGG  = NODES_SZ + GLOB_SZ;      // [B,G,D]
constexpr int WS_TOTAL = NODES_SZ + 2 * GLOB_SZ;  // floats (17.3 MB)
// (u16*)(ws + WS_TOTAL): WeT [128][512], then WnT [128][384]

__device__ inline u16 f2bf(float f) {
    union { float f; unsigned u; } v; v.f = f;
    return (u16)((v.u + 0x7fffu + ((v.u >> 16) & 1u)) >> 16);
}
__device__ inline short8 pack8(float4 a, float4 b) {
    short8 r;
    r[0] = (short)f2bf(a.x); r[1] = (short)f2bf(a.y);
    r[2] = (short)f2bf(a.z); r[3] = (short)f2bf(a.w);
    r[4] = (short)f2bf(b.x); r[5] = (short)f2bf(b.y);
    r[6] = (short)f2bf(b.z); r[7] = (short)f2bf(b.w);
    return r;
}

__global__ __launch_bounds__(256) void prep_w(
    const float* __restrict__ We, const float* __restrict__ Wn,
    u16* __restrict__ WeT, u16* __restrict__ WnT) {
    const int i = blockIdx.x * blockDim.x + threadIdx.x;
    if (i < DD * 512) {                       // WeT[n][k] = bf16(We[k][n])
        const int n = i >> 9, k = i & 511;
        WeT[i] = f2bf(We[k * DD + n]);
    } else {
        const int j = i - DD * 512;
        if (j < DD * 384) {                   // WnT[n][k] = bf16(Wn[k][n])
            const int n = j / 384, k = j - n * 384;
            WnT[j] = f2bf(Wn[k * DD + n]);
        }
    }
}

__global__ __launch_bounds__(256) void zero_ws(float4* ws, int n4) {
    int i = blockIdx.x * blockDim.x + threadIdx.x;
    const int stride = gridDim.x * blockDim.x;
    const float4 z = {0.f, 0.f, 0.f, 0.f};
    for (; i < n4; i += stride) ws[i] = z;
}

__global__ __launch_bounds__(256) void copy_idx(
    const int* __restrict__ recv, const int* __restrict__ send,
    const int* __restrict__ ngi, const int* __restrict__ egi,
    float* __restrict__ out) {
    int i = blockIdx.x * blockDim.x + threadIdx.x;
    const int stride = gridDim.x * blockDim.x;
    const int total = 3 * BE_ + BN_;
    for (; i < total; i += stride) {
        if (i < BE_)                 out[OFF_RECV + i] = (float)recv[i];
        else if (i < 2 * BE_)        out[OFF_SEND + (i - BE_)] = (float)send[i - BE_];
        else if (i < 2 * BE_ + BN_)  out[OFF_NGI + (i - 2 * BE_)] = (float)ngi[i - 2 * BE_];
        else                         out[OFF_EGI + (i - 2 * BE_ - BN_)] = (float)egi[i - 2 * BE_ - BN_];
    }
}

// ---------------- edge block: 64 rows/block, K=512 (2 chunks of 256) ------
__global__ __launch_bounds__(256) void edge_mfma(
    const float* __restrict__ nodes, const float* __restrict__ edges,
    const int* __restrict__ receivers, const int* __restrict__ senders,
    const float* __restrict__ glob, const int* __restrict__ egi,
    const u16* __restrict__ WeT, const float* __restrict__ be,
    const float* __restrict__ w_res,
    float* __restrict__ out, float* __restrict__ adj, float* __restrict__ eagg) {
    __shared__ float agg[64 * DD];            // 32 KB; A bf16 tile aliases it
    char* Ab = (char*)agg;

    const int tid = threadIdx.x;
    const int row0 = blockIdx.x * 64;
    const int bb = row0 >> 14;                // batch (E = 16384 rows/batch)

    // staging role: 4 threads per row, 64 fp32 (=16 float4) each per chunk
    const int srow = tid >> 2, q = tid & 3;
    const int sge = row0 + srow;
    const float* s_e = edges + (long)sge * DD;
    const float* s_s = nodes + ((long)bb * N_ + senders[sge]) * DD;
    const float* s_r = nodes + ((long)bb * N_ + receivers[sge]) * DD;
    const float* s_g = glob  + ((long)bb * G_ + egi[sge]) * DD;
    const float* sp_c0 = (q & 2) ? s_s : s_e;  // chunk0: k 0..255
    const float* sp_c1 = (q & 2) ? s_g : s_r;  // chunk1: k 256..511
    const int off0 = (q & 1) * 64;
    char* Asrow = Ab + srow * 512;
    const int sswz = (srow & 7) << 4;

    // mfma role: wave w owns rows [16w,16w+16), all 128 cols (8 n-tiles)
    const int l = tid & 63, w = tid >> 6;
    const int fr = l & 15, fg = l >> 4;
    char* Afrag = Ab + (16 * w + fr) * 512;
    const int aswz = (fr & 7) << 4;

    f32x4 acc[8];
    const f32x4 fz = {0.f, 0.f, 0.f, 0.f};
    #pragma unroll
    for (int i = 0; i < 8; ++i) acc[i] = fz;

    #pragma unroll
    for (int kc = 0; kc < 2; ++kc) {
        const float* sp = kc ? sp_c1 : sp_c0;
        __syncthreads();
        #pragma unroll
        for (int j = 0; j < 4; ++j) {
            const float4 v0 = *(const float4*)(sp + off0 + j * 16);
            const float4 v1 = *(const float4*)(sp + off0 + j * 16 + 4);
            const float4 v2 = *(const float4*)(sp + off0 + j * 16 + 8);
            const float4 v3 = *(const float4*)(sp + off0 + j * 16 + 12);
            *(short8*)(Asrow + ((q * 128 + j * 32) ^ sswz)) = pack8(v0, v1);
            *(short8*)(Asrow + ((q * 128 + j * 32 + 16) ^ sswz)) = pack8(v2, v3);
        }
        __syncthreads();
        const u16* bp = WeT + kc * 256 + fg * 8 + (long)fr * 512;
        #pragma unroll
        for (int ks = 0; ks < 8; ++ks) {
            const short8 a = *(const short8*)(Afrag + ((ks * 64 + fg * 16) ^ aswz));
            #pragma unroll
            for (int nt = 0; nt < 8; ++nt) {
                const short8 b = *(const short8*)(bp + nt * 8192 + ks * 32);
                acc[nt] = __builtin_amdgcn_mfma_f32_16x16x32_bf16(a, b, acc[nt], 0, 0, 0);
            }
        }
    }

    // epilogue: u = relu(acc + bias); edges_out; adj atomics; LDS eagg
    const float wr = w_res[0];
    int rcv[4], gg[4];
    #pragma unroll
    for (int r = 0; r < 4; ++r) {
        const int ge = row0 + 16 * w + fg * 4 + r;
        rcv[r] = receivers[ge];
        gg[r] = egi[ge];
    }
    #pragma unroll
    for (int nt = 0; nt < 8; ++nt) {
        const int c = nt * 16 + fr;
        const float bias = be[c];
        #pragma unroll
        for (int r = 0; r < 4; ++r) {
            const float u = fmaxf(acc[nt][r] + bias, 0.f);
            acc[nt][r] = u;
            const long ge = row0 + 16 * w + fg * 4 + r;
            out[OFF_EDGES + ge * DD + c] = edges[ge * DD + c] + wr * u;
            atomicAdd(adj + ((long)bb * N_ + rcv[r]) * DD + c, u);
        }
    }
    __syncthreads();     // everyone done with A tile -> reuse as agg
    #pragma unroll
    for (int j = 0; j < 8; ++j) {
        const float4 z = {0.f, 0.f, 0.f, 0.f};
        *(float4*)&agg[tid * 32 + j * 4] = z;
    }
    __syncthreads();
    #pragma unroll
    for (int nt = 0; nt < 8; ++nt) {
        #pragma unroll
        for (int r = 0; r < 4; ++r)
            atomicAdd(&agg[gg[r] * DD + nt * 16 + fr], acc[nt][r]);
    }
    __syncthreads();
    #pragma unroll
    for (int j = 0; j < 8; ++j) {
        const int base = tid * 32 + j * 4;
        const float4 v = *(float4*)&agg[base];
        float* dst = eagg + ((long)bb * G_ + (base >> 7)) * DD + (base & 127);
        if (v.x != 0.f) atomicAdd(dst + 0, v.x);
        if (v.y != 0.f) atomicAdd(dst + 1, v.y);
        if (v.z != 0.f) atomicAdd(dst + 2, v.z);
        if (v.w != 0.f) atomicAdd(dst + 3, v.w);
    }
}

// ---------------- node block: 64 rows/block, K=384 (3 chunks of 128) ------
__global__ __launch_bounds__(256) void node_mfma(
    const float* __restrict__ nodes, const float* __restrict__ adj,
    const float* __restrict__ glob, const int* __restrict__ ngi,
    const u16* __restrict__ WnT, const float* __restrict__ bn,
    const float* __restrict__ w_res,
    float* __restrict__ out, float* __restrict__ nagg) {
    __shared__ float agg[64 * DD];            // 32 KB; A tile (16KB) aliases
    char* Ab = (char*)agg;

    const int tid = threadIdx.x;
    const int row0 = blockIdx.x * 64;
    const int bb = row0 >> 12;                // batch (N = 4096 rows/batch)

    const int srow = tid >> 2, q = tid & 3;
    const int sgn = row0 + srow;
    const float* s_n = nodes + (long)sgn * DD;
    const float* s_a = adj   + (long)sgn * DD;
    const float* s_g = glob  + ((long)bb * G_ + ngi[sgn]) * DD;
    const int off0 = q * 32;
    char* Asrow = Ab + srow * 256;
    const int sswz = (srow & 7) << 4;

    const int l = tid & 63, w = tid >> 6;
    const int fr = l & 15, fg = l >> 4;
    char* Afrag = Ab + (16 * w + fr) * 256;
    const int aswz = (fr & 7) << 4;

    f32x4 acc[8];
    const f32x4 fz = {0.f, 0.f, 0.f, 0.f};
    #pragma unroll
    for (int i = 0; i < 8; ++i) acc[i] = fz;

    #pragma unroll
    for (int kc = 0; kc < 3; ++kc) {
        const float* sp = (kc == 0) ? s_n : (kc == 1) ? s_a : s_g;
        __syncthreads();
        #pragma unroll
        for (int j2 = 0; j2 < 2; ++j2) {
            const float4 v0 = *(const float4*)(sp + off0 + j2 * 16);
            const float4 v1 = *(const float4*)(sp + off0 + j2 * 16 + 4);
            const float4 v2 = *(const float4*)(sp + off0 + j2 * 16 + 8);
            const float4 v3 = *(const float4*)(sp + off0 + j2 * 16 + 12);
            *(short8*)(Asrow + ((q * 64 + j2 * 32) ^ sswz)) = pack8(v0, v1);
            *(short8*)(Asrow + ((q * 64 + j2 * 32 + 16) ^ sswz)) = pack8(v2, v3);
        }
        __syncthreads();
        const u16* bp = WnT + kc * 128 + fg * 8 + (long)fr * 384;
        #pragma unroll
        for (int ks = 0; ks < 4; ++ks) {
            const short8 a = *(const short8*)(Afrag + ((ks * 64 + fg * 16) ^ aswz));
            #pragma unroll
            for (int nt = 0; nt < 8; ++nt) {
                const short8 b = *(const short8*)(bp + nt * 6144 + ks * 32);
                acc[nt] = __builtin_amdgcn_mfma_f32_16x16x32_bf16(a, b, acc[nt], 0, 0, 0);
            }
        }
    }

    const float wr = w_res[0];
    int gg[4];
    #pragma unroll
    for (int r = 0; r < 4; ++r) gg[r] = ngi[row0 + 16 * w + fg * 4 + r];

    #pragma unroll
    for (int nt = 0; nt < 8; ++nt) {
        const int c = nt * 16 + fr;
        const float bias = bn[c];
        #pragma unroll
        for (int r = 0; r < 4; ++r) {
            const float u = fmaxf(acc[nt][r] + bias, 0.f);
            acc[nt][r] = u;
            const long gn = row0 + 16 * w + fg * 4 + r;
            out[OFF_NODES + gn * DD + c] = nodes[gn * DD + c] + wr * u;
        }
    }
    __syncthreads();
    #pragma unroll
    for (int j = 0; j < 8; ++j) {
        const float4 z = {0.f, 0.f, 0.f, 0.f};
        *(float4*)&agg[tid * 32 + j * 4] = z;
    }
    __syncthreads();
    #pragma unroll
    for (int nt = 0; nt < 8; ++nt) {
        #pragma unroll
        for (int r = 0; r < 4; ++r)
            atomicAdd(&agg[gg[r] * DD + nt * 16 + fr], acc[nt][r]);
    }
    __syncthreads();
    #pragma unroll
    for (int j = 0; j < 8; ++j) {
        const int base = tid * 32 + j * 4;
        const float4 v = *(float4*)&agg[base];
        float* dst = nagg + ((long)bb * G_ + (base >> 7)) * DD + (base & 127);
        if (v.x != 0.f) atomicAdd(dst + 0, v.x);
        if (v.y != 0.f) atomicAdd(dst + 1, v.y);
        if (v.z != 0.f) atomicAdd(dst + 2, v.z);
        if (v.w != 0.f) atomicAdd(dst + 3, v.w);
    }
}

// ---------------- global block: 512 rows, K=384, fp32 VALU ----------------
__global__ __launch_bounds__(128) void global_block(
    const float* __restrict__ nagg, const float* __restrict__ eagg,
    const float* __restrict__ glob,
    const float* __restrict__ Wg, const float* __restrict__ bg,
    const float* __restrict__ w_res, float* __restrict__ out) {
    __shared__ float gin[384];
    const int row = blockIdx.x;
    const int tid = threadIdx.x;
    gin[tid]       = nagg[row * DD + tid];
    gin[128 + tid] = eagg[row * DD + tid];
    gin[256 + tid] = glob[row * DD + tid];
    __syncthreads();
    float acc = bg[tid];
    #pragma unroll 4
    for (int k = 0; k < 384; ++k) acc += gin[k] * Wg[k * DD + tid];
    const float upd = fmaxf(acc, 0.f);
    out[OFF_GLOB + row * DD + tid] = glob[row * DD + tid] + w_res[0] * upd;
}

extern "C" void kernel_launch(void* const* d_in, const int* in_sizes, int n_in,
                              void* d_out, int out_size, void* d_ws, size_t ws_size,
                              hipStream_t stream) {
    const float* nodes     = (const float*)d_in[0];
    const float* edges     = (const float*)d_in[1];
    const int*   receivers = (const int*)d_in[2];
    const int*   senders   = (const int*)d_in[3];
    const float* glob      = (const float*)d_in[4];
    const int*   ngi       = (const int*)d_in[5];
    const int*   egi       = (const int*)d_in[6];
    const float* We        = (const float*)d_in[7];
    const float* be        = (const float*)d_in[8];
    const float* Wn        = (const float*)d_in[9];
    const float* bn        = (const float*)d_in[10];
    const float* Wg        = (const float*)d_in[11];
    const float* bg        = (const float*)d_in[12];
    const float* w_res     = (const float*)d_in[13];
    float* out = (float*)d_out;
    float* ws  = (float*)d_ws;
    float* adj  = ws + WS_ADJ;
    float* eagg = ws + WS_EAGG;
    float* nagg = ws + WS_NAGG;
    u16* WeT = (u16*)(ws + WS_TOTAL);
    u16* WnT = WeT + DD * 512;

    hipLaunchKernelGGL(prep_w, dim3(448), dim3(256), 0, stream, We, Wn, WeT, WnT);
    hipLaunchKernelGGL(zero_ws, dim3(1024), dim3(256), 0, stream,
                       (float4*)ws, WS_TOTAL / 4);
    hipLaunchKernelGGL(copy_idx, dim3(512), dim3(256), 0, stream,
                       receivers, senders, ngi, egi, out);
    hipLaunchKernelGGL(edge_mfma, dim3(BE_ / 64), dim3(256), 0, stream,
                       nodes, edges, receivers, senders, glob, egi, WeT, be, w_res,
                       out, adj, eagg);
    hipLaunchKernelGGL(node_mfma, dim3(BN_ / 64), dim3(256), 0, stream,
                       nodes, adj, glob, ngi, WnT, bn, w_res, out, nagg);
    hipLaunchKernelGGL(global_block, dim3(BG_), dim3(128), 0, stream,
                       nagg, eagg, glob, Wg, bg, w_res, out);
}

// Round 3
// 338.001 us; speedup vs baseline: 2.1060x; 2.0235x over previous
//
#include <hip/hip_runtime.h>

// GraphNetworkLayer: B=8, N=4096, E=16384, G=64, D=128, fp32 in/out.
// Round 3: atomic-free. All segment-sums are gathers:
//  - adj: per-batch CSR (int-atomic build, ~262K int atomics) gathered inside
//    node_mfma's A-tile staging (fp32 register accumulate -> bf16 LDS).
//  - eagg/nagg: one block per (b,g) scans indices in LDS chunks, compresses
//    matches, gathers rows; fuses the residual write (out = in + wr*u) since
//    each row belongs to exactly one group.
//  - edge/node MFMA kernels write u = relu(GEMM+bias) fp32 to d_out regions
//    (LDS-bounced coalesced float4 stores); no float atomics anywhere.

#define DD 128
typedef unsigned short u16;
typedef __attribute__((ext_vector_type(8))) short short8;   // 8 bf16
typedef __attribute__((ext_vector_type(4))) float f32x4;

constexpr int B_ = 8, N_ = 4096, E_ = 16384, G_ = 64;
constexpr int NODES_SZ = B_ * N_ * DD;   // 4,194,304
constexpr int EDGES_SZ = B_ * E_ * DD;   // 16,777,216
constexpr int BE_ = B_ * E_;             // 131,072
constexpr int BN_ = B_ * N_;             // 32,768
constexpr int BG_ = B_ * G_;             // 512
constexpr int GLOB_SZ = BG_ * DD;        // 65,536

constexpr int OFF_NODES = 0;
constexpr int OFF_EDGES = OFF_NODES + NODES_SZ;
constexpr int OFF_RECV  = OFF_EDGES + EDGES_SZ;
constexpr int OFF_SEND  = OFF_RECV + BE_;
constexpr int OFF_GLOB  = OFF_SEND + BE_;
constexpr int OFF_NGI   = OFF_GLOB + GLOB_SZ;
constexpr int OFF_EGI   = OFF_NGI + BN_;

// ws layout (float elements)
constexpr int WS_EAGG  = 0;               // [B,G,D] f32
constexpr int WS_NAGG  = WS_EAGG + GLOB_SZ;
constexpr int WS_CNT   = WS_NAGG + GLOB_SZ;          // [B*N] int
constexpr int WS_RS    = WS_CNT + BN_;               // [B*N] int (row starts)
constexpr int WS_CUR   = WS_RS + BN_;                // [B*N] int (fill cursor)
constexpr int WS_ELIST = WS_CUR + BN_;               // [B*E] int
constexpr int WS_WET   = WS_ELIST + BE_;             // u16[128*512] (32768 f)
constexpr int WS_WNT   = WS_WET + 32768;             // u16[128*384] (24576 f)

__device__ inline u16 f2bf(float f) {
    union { float f; unsigned u; } v; v.f = f;
    return (u16)((v.u + 0x7fffu + ((v.u >> 16) & 1u)) >> 16);
}
__device__ inline short8 pack8(float4 a, float4 b) {
    short8 r;
    r[0] = (short)f2bf(a.x); r[1] = (short)f2bf(a.y);
    r[2] = (short)f2bf(a.z); r[3] = (short)f2bf(a.w);
    r[4] = (short)f2bf(b.x); r[5] = (short)f2bf(b.y);
    r[6] = (short)f2bf(b.z); r[7] = (short)f2bf(b.w);
    return r;
}

__global__ __launch_bounds__(256) void prep_w(
    const float* __restrict__ We, const float* __restrict__ Wn,
    u16* __restrict__ WeT, u16* __restrict__ WnT) {
    const int i = blockIdx.x * blockDim.x + threadIdx.x;
    if (i < DD * 512) {                       // WeT[n][k] = bf16(We[k][n])
        const int n = i >> 9, k = i & 511;
        WeT[i] = f2bf(We[k * DD + n]);
    } else {
        const int j = i - DD * 512;
        if (j < DD * 384) {                   // WnT[n][k] = bf16(Wn[k][n])
            const int n = j / 384, k = j - n * 384;
            WnT[j] = f2bf(Wn[k * DD + n]);
        }
    }
}

__global__ __launch_bounds__(256) void zero_cnt(int4* cnt) {
    const int i = blockIdx.x * 256 + threadIdx.x;   // 8192 int4 = 32768 ints
    const int4 z = {0, 0, 0, 0};
    cnt[i] = z;
}

__global__ __launch_bounds__(256) void copy_idx(
    const int* __restrict__ recv, const int* __restrict__ send,
    const int* __restrict__ ngi, const int* __restrict__ egi,
    float* __restrict__ out) {
    int i = blockIdx.x * blockDim.x + threadIdx.x;
    const int stride = gridDim.x * blockDim.x;
    const int total = 3 * BE_ + BN_;
    for (; i < total; i += stride) {
        if (i < BE_)                 out[OFF_RECV + i] = (float)recv[i];
        else if (i < 2 * BE_)        out[OFF_SEND + (i - BE_)] = (float)send[i - BE_];
        else if (i < 2 * BE_ + BN_)  out[OFF_NGI + (i - 2 * BE_)] = (float)ngi[i - 2 * BE_];
        else                         out[OFF_EGI + (i - 2 * BE_ - BN_)] = (float)egi[i - 2 * BE_ - BN_];
    }
}

// ---------- CSR build for receiver lists ----------
__global__ __launch_bounds__(256) void k_hist(
    const int* __restrict__ recv, int* __restrict__ cnt) {
    const int e = blockIdx.x * 256 + threadIdx.x;   // 0..131071
    atomicAdd(&cnt[(e >> 14) * N_ + recv[e]], 1);
}

__global__ __launch_bounds__(1024) void k_scan(
    const int* __restrict__ cnt, int* __restrict__ rs, int* __restrict__ cur) {
    __shared__ int s[1024];
    const int b = blockIdx.x;          // batch
    const int t = threadIdx.x;
    const int base = b * N_;
    int c[4];
    int sum = 0;
    #pragma unroll
    for (int i = 0; i < 4; ++i) { c[i] = cnt[base + 4 * t + i]; sum += c[i]; }
    s[t] = sum;
    __syncthreads();
    for (int off = 1; off < 1024; off <<= 1) {   // inclusive Hillis-Steele
        int v = s[t];
        if (t >= off) v += s[t - off];
        __syncthreads();
        s[t] = v;
        __syncthreads();
    }
    int eb = s[t] - sum;               // exclusive prefix (within batch)
    #pragma unroll
    for (int i = 0; i < 4; ++i) {
        rs[base + 4 * t + i] = eb;
        cur[base + 4 * t + i] = eb;
        eb += c[i];
    }
}

__global__ __launch_bounds__(256) void k_fill(
    const int* __restrict__ recv, int* __restrict__ cur, int* __restrict__ elist) {
    const int e = blockIdx.x * 256 + threadIdx.x;
    const int b = e >> 14;
    const int slot = atomicAdd(&cur[b * N_ + recv[e]], 1);
    elist[b * E_ + slot] = e;          // global edge id, grouped by receiver
}

// ---------------- edge block: 64 rows/block, K=512 ----------------
__global__ __launch_bounds__(256) void edge_mfma(
    const float* __restrict__ nodes, const float* __restrict__ edges,
    const int* __restrict__ receivers, const int* __restrict__ senders,
    const float* __restrict__ glob, const int* __restrict__ egi,
    const u16* __restrict__ WeT, const float* __restrict__ be,
    float* __restrict__ out) {
    __shared__ float agg[64 * DD];            // 32 KB; aliases A bf16 tile
    char* Ab = (char*)agg;

    const int tid = threadIdx.x;
    const int row0 = blockIdx.x * 64;
    const int bb = row0 >> 14;

    const int srow = tid >> 2, q = tid & 3;
    const int sge = row0 + srow;
    const float* s_e = edges + (long)sge * DD;
    const float* s_s = nodes + ((long)bb * N_ + senders[sge]) * DD;
    const float* s_r = nodes + ((long)bb * N_ + receivers[sge]) * DD;
    const float* s_g = glob  + ((long)bb * G_ + egi[sge]) * DD;
    const float* sp_c0 = (q & 2) ? s_s : s_e;  // chunk0: k 0..255
    const float* sp_c1 = (q & 2) ? s_g : s_r;  // chunk1: k 256..511
    const int off0 = (q & 1) * 64;
    char* Asrow = Ab + srow * 512;
    const int sswz = (srow & 7) << 4;

    const int l = tid & 63, w = tid >> 6;
    const int fr = l & 15, fg = l >> 4;
    char* Afrag = Ab + (16 * w + fr) * 512;
    const int aswz = (fr & 7) << 4;

    f32x4 acc[8];
    const f32x4 fz = {0.f, 0.f, 0.f, 0.f};
    #pragma unroll
    for (int i = 0; i < 8; ++i) acc[i] = fz;

    #pragma unroll
    for (int kc = 0; kc < 2; ++kc) {
        const float* sp = kc ? sp_c1 : sp_c0;
        __syncthreads();
        #pragma unroll
        for (int j = 0; j < 4; ++j) {
            const float4 v0 = *(const float4*)(sp + off0 + j * 16);
            const float4 v1 = *(const float4*)(sp + off0 + j * 16 + 4);
            const float4 v2 = *(const float4*)(sp + off0 + j * 16 + 8);
            const float4 v3 = *(const float4*)(sp + off0 + j * 16 + 12);
            *(short8*)(Asrow + ((q * 128 + j * 32) ^ sswz)) = pack8(v0, v1);
            *(short8*)(Asrow + ((q * 128 + j * 32 + 16) ^ sswz)) = pack8(v2, v3);
        }
        __syncthreads();
        const u16* bp = WeT + kc * 256 + fg * 8 + (long)fr * 512;
        #pragma unroll
        for (int ks = 0; ks < 8; ++ks) {
            const short8 a = *(const short8*)(Afrag + ((ks * 64 + fg * 16) ^ aswz));
            #pragma unroll
            for (int nt = 0; nt < 8; ++nt) {
                const short8 b = *(const short8*)(bp + nt * 8192 + ks * 32);
                acc[nt] = __builtin_amdgcn_mfma_f32_16x16x32_bf16(a, b, acc[nt], 0, 0, 0);
            }
        }
    }

    // epilogue: u = relu(acc+bias) -> LDS -> coalesced float4 store of u
    __syncthreads();
    #pragma unroll
    for (int nt = 0; nt < 8; ++nt) {
        const float bias = be[nt * 16 + fr];
        #pragma unroll
        for (int r = 0; r < 4; ++r)
            agg[(16 * w + fg * 4 + r) * DD + nt * 16 + fr] =
                fmaxf(acc[nt][r] + bias, 0.f);
    }
    __syncthreads();
    const long ob = (long)OFF_EDGES + (long)row0 * DD;
    #pragma unroll
    for (int j = 0; j < 8; ++j)
        *(float4*)(out + ob + j * 1024 + tid * 4) =
            *(const float4*)&agg[j * 1024 + tid * 4];
}

// ---------------- node block: 64 rows/block, K=384 ----------------
__global__ __launch_bounds__(256) void node_mfma(
    const float* __restrict__ nodes, const float* __restrict__ glob,
    const int* __restrict__ ngi,
    const int* __restrict__ rs, const int* __restrict__ cnt,
    const int* __restrict__ elist,
    const u16* __restrict__ WnT, const float* __restrict__ bn,
    float* __restrict__ out) {
    __shared__ float agg[64 * DD];            // 32 KB; A tile uses 16 KB
    char* Ab = (char*)agg;

    const int tid = threadIdx.x;
    const int row0 = blockIdx.x * 64;
    const int bb = row0 >> 12;

    const int srow = tid >> 2, q = tid & 3;
    const int sgn = row0 + srow;
    const float* s_n = nodes + (long)sgn * DD;
    const float* s_g = glob  + ((long)bb * G_ + ngi[sgn]) * DD;
    const int off0 = q * 32;
    char* Asrow = Ab + srow * 256;
    const int sswz = (srow & 7) << 4;
    const float* uE = out + OFF_EDGES;        // u rows from edge kernel

    const int l = tid & 63, w = tid >> 6;
    const int fr = l & 15, fg = l >> 4;
    char* Afrag = Ab + (16 * w + fr) * 256;
    const int aswz = (fr & 7) << 4;

    f32x4 acc[8];
    const f32x4 fz = {0.f, 0.f, 0.f, 0.f};
    #pragma unroll
    for (int i = 0; i < 8; ++i) acc[i] = fz;

    #pragma unroll
    for (int kc = 0; kc < 3; ++kc) {
        __syncthreads();
        if (kc == 1) {
            // adj chunk: CSR gather + fp32 register segment-sum
            float4 fa[8];
            #pragma unroll
            for (int j = 0; j < 8; ++j) fa[j] = {0.f, 0.f, 0.f, 0.f};
            const int start = rs[sgn], deg = cnt[sgn];
            const int* lp = elist + (long)bb * E_ + start;
            for (int i = 0; i < deg; ++i) {
                const float* up = uE + (long)lp[i] * DD + off0;
                #pragma unroll
                for (int j = 0; j < 8; ++j) {
                    const float4 v = *(const float4*)(up + j * 4);
                    fa[j].x += v.x; fa[j].y += v.y; fa[j].z += v.z; fa[j].w += v.w;
                }
            }
            *(short8*)(Asrow + ((q * 64 +  0) ^ sswz)) = pack8(fa[0], fa[1]);
            *(short8*)(Asrow + ((q * 64 + 16) ^ sswz)) = pack8(fa[2], fa[3]);
            *(short8*)(Asrow + ((q * 64 + 32) ^ sswz)) = pack8(fa[4], fa[5]);
            *(short8*)(Asrow + ((q * 64 + 48) ^ sswz)) = pack8(fa[6], fa[7]);
        } else {
            const float* sp = (kc == 0) ? s_n : s_g;
            #pragma unroll
            for (int j2 = 0; j2 < 2; ++j2) {
                const float4 v0 = *(const float4*)(sp + off0 + j2 * 16);
                const float4 v1 = *(const float4*)(sp + off0 + j2 * 16 + 4);
                const float4 v2 = *(const float4*)(sp + off0 + j2 * 16 + 8);
                const float4 v3 = *(const float4*)(sp + off0 + j2 * 16 + 12);
                *(short8*)(Asrow + ((q * 64 + j2 * 32) ^ sswz)) = pack8(v0, v1);
                *(short8*)(Asrow + ((q * 64 + j2 * 32 + 16) ^ sswz)) = pack8(v2, v3);
            }
        }
        __syncthreads();
        const u16* bp = WnT + kc * 128 + fg * 8 + (long)fr * 384;
        #pragma unroll
        for (int ks = 0; ks < 4; ++ks) {
            const short8 a = *(const short8*)(Afrag + ((ks * 64 + fg * 16) ^ aswz));
            #pragma unroll
            for (int nt = 0; nt < 8; ++nt) {
                const short8 b = *(const short8*)(bp + nt * 6144 + ks * 32);
                acc[nt] = __builtin_amdgcn_mfma_f32_16x16x32_bf16(a, b, acc[nt], 0, 0, 0);
            }
        }
    }

    __syncthreads();
    #pragma unroll
    for (int nt = 0; nt < 8; ++nt) {
        const float bias = bn[nt * 16 + fr];
        #pragma unroll
        for (int r = 0; r < 4; ++r)
            agg[(16 * w + fg * 4 + r) * DD + nt * 16 + fr] =
                fmaxf(acc[nt][r] + bias, 0.f);
    }
    __syncthreads();
    const long ob = (long)OFF_NODES + (long)row0 * DD;
    #pragma unroll
    for (int j = 0; j < 8; ++j)
        *(float4*)(out + ob + j * 1024 + tid * 4) =
            *(const float4*)&agg[j * 1024 + tid * 4];
}

// -------- agg + residual: one block per (b,g); no float atomics --------
__global__ __launch_bounds__(256) void agg_scan(
    const float* __restrict__ edges_in, const float* __restrict__ nodes_in,
    const int* __restrict__ egi, const int* __restrict__ ngi,
    const float* __restrict__ w_res,
    float* __restrict__ out, float* __restrict__ eagg, float* __restrict__ nagg) {
    __shared__ int idxl[256];
    __shared__ int lst[256];
    __shared__ int cntm;
    __shared__ float accl[256];
    const int tid = threadIdx.x;
    const int col = tid & 127, sub = tid >> 7;
    const float wr = w_res[0];
    float acc = 0.f;

    if (blockIdx.x < 512) {
        const int b = blockIdx.x >> 6, g = blockIdx.x & 63;
        const int* gi = egi + b * E_;
        const float* uRow = out + OFF_EDGES + (long)b * E_ * DD;
        const float* inRow = edges_in + (long)b * E_ * DD;
        float* oRow = out + OFF_EDGES + (long)b * E_ * DD;
        for (int c0 = 0; c0 < E_; c0 += 256) {
            if (tid == 0) cntm = 0;
            idxl[tid] = gi[c0 + tid];
            __syncthreads();
            if (idxl[tid] == g) { const int p = atomicAdd(&cntm, 1); lst[p] = tid; }
            __syncthreads();
            const int m = cntm;
            for (int j = sub; j < m; j += 2) {
                const long re = (long)(c0 + lst[j]) * DD + col;
                const float v = uRow[re];
                acc += v;
                oRow[re] = inRow[re] + wr * v;
            }
            __syncthreads();
        }
        accl[tid] = acc;
        __syncthreads();
        if (tid < 128)
            eagg[((long)b * G_ + g) * DD + tid] = accl[tid] + accl[tid + 128];
    } else {
        const int gid = blockIdx.x - 512;
        const int b = gid >> 6, g = gid & 63;
        const int* gi = ngi + b * N_;
        const float* uRow = out + OFF_NODES + (long)b * N_ * DD;
        const float* inRow = nodes_in + (long)b * N_ * DD;
        float* oRow = out + OFF_NODES + (long)b * N_ * DD;
        for (int c0 = 0; c0 < N_; c0 += 256) {
            if (tid == 0) cntm = 0;
            idxl[tid] = gi[c0 + tid];
            __syncthreads();
            if (idxl[tid] == g) { const int p = atomicAdd(&cntm, 1); lst[p] = tid; }
            __syncthreads();
            const int m = cntm;
            for (int j = sub; j < m; j += 2) {
                const long re = (long)(c0 + lst[j]) * DD + col;
                const float v = uRow[re];
                acc += v;
                oRow[re] = inRow[re] + wr * v;
            }
            __syncthreads();
        }
        accl[tid] = acc;
        __syncthreads();
        if (tid < 128)
            nagg[((long)b * G_ + g) * DD + tid] = accl[tid] + accl[tid + 128];
    }
}

// ---------------- global block: 512 rows, K=384, fp32 VALU ----------------
__global__ __launch_bounds__(128) void global_block(
    const float* __restrict__ nagg, const float* __restrict__ eagg,
    const float* __restrict__ glob,
    const float* __restrict__ Wg, const float* __restrict__ bg,
    const float* __restrict__ w_res, float* __restrict__ out) {
    __shared__ float gin[384];
    const int row = blockIdx.x;
    const int tid = threadIdx.x;
    gin[tid]       = nagg[row * DD + tid];
    gin[128 + tid] = eagg[row * DD + tid];
    gin[256 + tid] = glob[row * DD + tid];
    __syncthreads();
    float acc = bg[tid];
    #pragma unroll 4
    for (int k = 0; k < 384; ++k) acc += gin[k] * Wg[k * DD + tid];
    const float upd = fmaxf(acc, 0.f);
    out[OFF_GLOB + row * DD + tid] = glob[row * DD + tid] + w_res[0] * upd;
}

extern "C" void kernel_launch(void* const* d_in, const int* in_sizes, int n_in,
                              void* d_out, int out_size, void* d_ws, size_t ws_size,
                              hipStream_t stream) {
    const float* nodes     = (const float*)d_in[0];
    const float* edges     = (const float*)d_in[1];
    const int*   receivers = (const int*)d_in[2];
    const int*   senders   = (const int*)d_in[3];
    const float* glob      = (const float*)d_in[4];
    const int*   ngi       = (const int*)d_in[5];
    const int*   egi       = (const int*)d_in[6];
    const float* We        = (const float*)d_in[7];
    const float* bn        = (const float*)d_in[10];
    const float* be        = (const float*)d_in[8];
    const float* Wn        = (const float*)d_in[9];
    const float* Wg        = (const float*)d_in[11];
    const float* bg        = (const float*)d_in[12];
    const float* w_res     = (const float*)d_in[13];
    float* out = (float*)d_out;
    float* ws  = (float*)d_ws;
    float* eagg = ws + WS_EAGG;
    float* nagg = ws + WS_NAGG;
    int* cnt   = (int*)(ws + WS_CNT);
    int* rs    = (int*)(ws + WS_RS);
    int* cur   = (int*)(ws + WS_CUR);
    int* elist = (int*)(ws + WS_ELIST);
    u16* WeT   = (u16*)(ws + WS_WET);
    u16* WnT   = (u16*)(ws + WS_WNT);

    hipLaunchKernelGGL(prep_w, dim3(448), dim3(256), 0, stream, We, Wn, WeT, WnT);
    hipLaunchKernelGGL(zero_cnt, dim3(32), dim3(256), 0, stream, (int4*)cnt);
    hipLaunchKernelGGL(copy_idx, dim3(512), dim3(256), 0, stream,
                       receivers, senders, ngi, egi, out);
    hipLaunchKernelGGL(k_hist, dim3(512), dim3(256), 0, stream, receivers, cnt);
    hipLaunchKernelGGL(k_scan, dim3(8), dim3(1024), 0, stream, cnt, rs, cur);
    hipLaunchKernelGGL(k_fill, dim3(512), dim3(256), 0, stream, receivers, cur, elist);
    hipLaunchKernelGGL(edge_mfma, dim3(BE_ / 64), dim3(256), 0, stream,
                       nodes, edges, receivers, senders, glob, egi, WeT, be, out);
    hipLaunchKernelGGL(node_mfma, dim3(BN_ / 64), dim3(256), 0, stream,
                       nodes, glob, ngi, rs, cnt, elist, WnT, bn, out);
    hipLaunchKernelGGL(agg_scan, dim3(1024), dim3(256), 0, stream,
                       edges, nodes, egi, ngi, w_res, out, eagg, nagg);
    hipLaunchKernelGGL(global_block, dim3(BG_), dim3(128), 0, stream,
                       nagg, eagg, glob, Wg, bg, w_res, out);
}

// Round 4
// 283.173 us; speedup vs baseline: 2.5137x; 1.1936x over previous
//
#include <hip/hip_runtime.h>

// GraphNetworkLayer: B=8, N=4096, E=16384, G=64, D=128, fp32 in/out.
// Round 4: LDS/barrier-free MFMA GEMMs. A-fragments gathered directly from
// global into registers (one 32B load per lane per k-step per row), packed to
// bf16 in-reg. M-rep=2 (32 rows/wave) halves B traffic. adj pre-aggregated
// (CSR gather) into a bf16 [B,N,D] ws buffer by adj_gather; node kernel reads
// it as ready-made short8 fragments. No float atomics anywhere.

#define DD 128
typedef unsigned short u16;
typedef __attribute__((ext_vector_type(8))) short short8;   // 8 bf16
typedef __attribute__((ext_vector_type(4))) float f32x4;

constexpr int B_ = 8, N_ = 4096, E_ = 16384, G_ = 64;
constexpr int NODES_SZ = B_ * N_ * DD;   // 4,194,304
constexpr int EDGES_SZ = B_ * E_ * DD;   // 16,777,216
constexpr int BE_ = B_ * E_;             // 131,072
constexpr int BN_ = B_ * N_;             // 32,768
constexpr int BG_ = B_ * G_;             // 512
constexpr int GLOB_SZ = BG_ * DD;        // 65,536

constexpr int OFF_NODES = 0;
constexpr int OFF_EDGES = OFF_NODES + NODES_SZ;
constexpr int OFF_RECV  = OFF_EDGES + EDGES_SZ;
constexpr int OFF_SEND  = OFF_RECV + BE_;
constexpr int OFF_GLOB  = OFF_SEND + BE_;
constexpr int OFF_NGI   = OFF_GLOB + GLOB_SZ;
constexpr int OFF_EGI   = OFF_NGI + BN_;

// ws layout (float-element offsets)
constexpr int WS_EAGG  = 0;                    // [B,G,D] f32
constexpr int WS_NAGG  = WS_EAGG + GLOB_SZ;
constexpr int WS_CNT   = WS_NAGG + GLOB_SZ;    // [B*N] int
constexpr int WS_RS    = WS_CNT + BN_;         // [B*N] int
constexpr int WS_CUR   = WS_RS + BN_;          // [B*N] int
constexpr int WS_ELIST = WS_CUR + BN_;         // [B*E] int
constexpr int WS_ADJB  = WS_ELIST + BE_;       // [B,N,D] bf16 (u16)
constexpr int WS_WET   = WS_ADJB + (BN_ * DD) / 2;  // u16[128*512]
constexpr int WS_WNT   = WS_WET + 32768;            // u16[128*384]
// total ~11 MB (< 17.5 MB proven in earlier rounds)

__device__ inline u16 f2bf(float f) {
    union { float f; unsigned u; } v; v.f = f;
    return (u16)((v.u + 0x7fffu + ((v.u >> 16) & 1u)) >> 16);
}
__device__ inline short8 pack8(float4 a, float4 b) {
    short8 r;
    r[0] = (short)f2bf(a.x); r[1] = (short)f2bf(a.y);
    r[2] = (short)f2bf(a.z); r[3] = (short)f2bf(a.w);
    r[4] = (short)f2bf(b.x); r[5] = (short)f2bf(b.y);
    r[6] = (short)f2bf(b.z); r[7] = (short)f2bf(b.w);
    return r;
}

__global__ __launch_bounds__(256) void prep_w(
    const float* __restrict__ We, const float* __restrict__ Wn,
    u16* __restrict__ WeT, u16* __restrict__ WnT) {
    const int i = blockIdx.x * blockDim.x + threadIdx.x;
    if (i < DD * 512) {                       // WeT[n][k] = bf16(We[k][n])
        const int n = i >> 9, k = i & 511;
        WeT[i] = f2bf(We[k * DD + n]);
    } else {
        const int j = i - DD * 512;
        if (j < DD * 384) {                   // WnT[n][k] = bf16(Wn[k][n])
            const int n = j / 384, k = j - n * 384;
            WnT[j] = f2bf(Wn[k * DD + n]);
        }
    }
}

__global__ __launch_bounds__(256) void zero_cnt(int4* cnt) {
    const int i = blockIdx.x * 256 + threadIdx.x;   // 8192 int4 = 32768 ints
    const int4 z = {0, 0, 0, 0};
    cnt[i] = z;
}

__global__ __launch_bounds__(256) void copy_idx(
    const int* __restrict__ recv, const int* __restrict__ send,
    const int* __restrict__ ngi, const int* __restrict__ egi,
    float* __restrict__ out) {
    int i = blockIdx.x * blockDim.x + threadIdx.x;
    const int stride = gridDim.x * blockDim.x;
    const int total = 3 * BE_ + BN_;
    for (; i < total; i += stride) {
        if (i < BE_)                 out[OFF_RECV + i] = (float)recv[i];
        else if (i < 2 * BE_)        out[OFF_SEND + (i - BE_)] = (float)send[i - BE_];
        else if (i < 2 * BE_ + BN_)  out[OFF_NGI + (i - 2 * BE_)] = (float)ngi[i - 2 * BE_];
        else                         out[OFF_EGI + (i - 2 * BE_ - BN_)] = (float)egi[i - 2 * BE_ - BN_];
    }
}

// ---------- CSR build for receiver lists ----------
__global__ __launch_bounds__(256) void k_hist(
    const int* __restrict__ recv, int* __restrict__ cnt) {
    const int e = blockIdx.x * 256 + threadIdx.x;
    atomicAdd(&cnt[(e >> 14) * N_ + recv[e]], 1);
}

__global__ __launch_bounds__(1024) void k_scan(
    const int* __restrict__ cnt, int* __restrict__ rs, int* __restrict__ cur) {
    __shared__ int s[1024];
    const int b = blockIdx.x;
    const int t = threadIdx.x;
    const int base = b * N_;
    int c[4];
    int sum = 0;
    #pragma unroll
    for (int i = 0; i < 4; ++i) { c[i] = cnt[base + 4 * t + i]; sum += c[i]; }
    s[t] = sum;
    __syncthreads();
    for (int off = 1; off < 1024; off <<= 1) {
        int v = s[t];
        if (t >= off) v += s[t - off];
        __syncthreads();
        s[t] = v;
        __syncthreads();
    }
    int eb = s[t] - sum;
    #pragma unroll
    for (int i = 0; i < 4; ++i) {
        rs[base + 4 * t + i] = eb;
        cur[base + 4 * t + i] = eb;
        eb += c[i];
    }
}

__global__ __launch_bounds__(256) void k_fill(
    const int* __restrict__ recv, int* __restrict__ cur, int* __restrict__ elist) {
    const int e = blockIdx.x * 256 + threadIdx.x;
    const int b = e >> 14;
    const int slot = atomicAdd(&cur[b * N_ + recv[e]], 1);
    elist[b * E_ + slot] = e;
}

// -------- edge GEMM: reg-direct A gather, no LDS, no barriers --------
// block = 256 thr (4 waves), wave covers 32 rows (M-rep 2), block 128 rows.
__global__ __launch_bounds__(256) void edge_mfma(
    const float* __restrict__ nodes, const float* __restrict__ edges,
    const int* __restrict__ receivers, const int* __restrict__ senders,
    const float* __restrict__ glob, const int* __restrict__ egi,
    const u16* __restrict__ WeT, const float* __restrict__ be,
    float* __restrict__ out) {
    const int tid = threadIdx.x;
    const int w = tid >> 6, l = tid & 63;
    const int fr = l & 15, fg = l >> 4;
    const int row0 = blockIdx.x * 128 + w * 32;
    const int bb = blockIdx.x >> 7;           // 128 blocks per batch
    const int R0 = row0 + fr, R1 = R0 + 16;

    const float* pA0[4] = {
        edges + (long)R0 * DD,
        nodes + ((long)bb * N_ + senders[R0]) * DD,
        nodes + ((long)bb * N_ + receivers[R0]) * DD,
        glob  + ((long)bb * G_ + egi[R0]) * DD};
    const float* pA1[4] = {
        edges + (long)R1 * DD,
        nodes + ((long)bb * N_ + senders[R1]) * DD,
        nodes + ((long)bb * N_ + receivers[R1]) * DD,
        glob  + ((long)bb * G_ + egi[R1]) * DD};

    float bias[8];
    #pragma unroll
    for (int nt = 0; nt < 8; ++nt) bias[nt] = be[nt * 16 + fr];

    f32x4 acc0[8], acc1[8];
    const f32x4 fz = {0.f, 0.f, 0.f, 0.f};
    #pragma unroll
    for (int i = 0; i < 8; ++i) { acc0[i] = fz; acc1[i] = fz; }

    const u16* bbp = WeT + (long)fr * 512 + fg * 8;

    #pragma unroll
    for (int seg = 0; seg < 4; ++seg) {       // k segments of 128
        const float* p0 = pA0[seg];
        const float* p1 = pA1[seg];
        #pragma unroll
        for (int ss = 0; ss < 4; ++ss) {      // k-steps of 32 within segment
            const int off = ss * 32 + fg * 8;
            const float4 x0 = *(const float4*)(p0 + off);
            const float4 y0 = *(const float4*)(p0 + off + 4);
            const float4 x1 = *(const float4*)(p1 + off);
            const float4 y1 = *(const float4*)(p1 + off + 4);
            const short8 a0 = pack8(x0, y0);
            const short8 a1 = pack8(x1, y1);
            const u16* bp = bbp + (seg * 4 + ss) * 32;
            #pragma unroll
            for (int nt = 0; nt < 8; ++nt) {
                const short8 b = *(const short8*)(bp + nt * 8192);
                acc0[nt] = __builtin_amdgcn_mfma_f32_16x16x32_bf16(a0, b, acc0[nt], 0, 0, 0);
                acc1[nt] = __builtin_amdgcn_mfma_f32_16x16x32_bf16(a1, b, acc1[nt], 0, 0, 0);
            }
        }
    }

    float* ob = out + OFF_EDGES;
    #pragma unroll
    for (int nt = 0; nt < 8; ++nt) {
        const int c = nt * 16 + fr;
        #pragma unroll
        for (int r = 0; r < 4; ++r) {
            const long rr = row0 + fg * 4 + r;
            ob[rr * DD + c] = fmaxf(acc0[nt][r] + bias[nt], 0.f);
            ob[(rr + 16) * DD + c] = fmaxf(acc1[nt][r] + bias[nt], 0.f);
        }
    }
}

// -------- adj = CSR gather-sum of u_e rows, written as bf16 --------
__global__ __launch_bounds__(256) void adj_gather(
    const int* __restrict__ rs, const int* __restrict__ cnt,
    const int* __restrict__ elist, const float* __restrict__ uE,
    u16* __restrict__ adjB) {
    const int tid = threadIdx.x;
    const int row = blockIdx.x * 64 + (tid >> 2);
    const int q = tid & 3;
    const int bb = row >> 12;
    const int start = rs[row], deg = cnt[row];
    const int* lp = elist + (long)bb * E_ + start;
    float4 a[8];
    #pragma unroll
    for (int j = 0; j < 8; ++j) a[j] = {0.f, 0.f, 0.f, 0.f};
    for (int i = 0; i < deg; ++i) {
        const float* up = uE + (long)lp[i] * DD + q * 32;
        #pragma unroll
        for (int j = 0; j < 8; ++j) {
            const float4 v = *(const float4*)(up + j * 4);
            a[j].x += v.x; a[j].y += v.y; a[j].z += v.z; a[j].w += v.w;
        }
    }
    u16* dst = adjB + (long)row * DD + q * 32;
    #pragma unroll
    for (int j = 0; j < 4; ++j)
        *(short8*)(dst + j * 8) = pack8(a[2 * j], a[2 * j + 1]);
}

// -------- node GEMM: same reg-direct structure, K=384 --------
__global__ __launch_bounds__(256) void node_mfma(
    const float* __restrict__ nodes, const u16* __restrict__ adjB,
    const float* __restrict__ glob, const int* __restrict__ ngi,
    const u16* __restrict__ WnT, const float* __restrict__ bn,
    float* __restrict__ out) {
    const int tid = threadIdx.x;
    const int w = tid >> 6, l = tid & 63;
    const int fr = l & 15, fg = l >> 4;
    const int row0 = blockIdx.x * 128 + w * 32;
    const int bb = blockIdx.x >> 5;           // 32 blocks per batch
    const int R0 = row0 + fr, R1 = R0 + 16;

    const float* pn0 = nodes + (long)R0 * DD;
    const float* pn1 = nodes + (long)R1 * DD;
    const u16*   pa0 = adjB + (long)R0 * DD;
    const u16*   pa1 = adjB + (long)R1 * DD;
    const float* pg0 = glob + ((long)bb * G_ + ngi[R0]) * DD;
    const float* pg1 = glob + ((long)bb * G_ + ngi[R1]) * DD;

    float bias[8];
    #pragma unroll
    for (int nt = 0; nt < 8; ++nt) bias[nt] = bn[nt * 16 + fr];

    f32x4 acc0[8], acc1[8];
    const f32x4 fz = {0.f, 0.f, 0.f, 0.f};
    #pragma unroll
    for (int i = 0; i < 8; ++i) { acc0[i] = fz; acc1[i] = fz; }

    const u16* bbp = WnT + (long)fr * 384 + fg * 8;

    #pragma unroll
    for (int seg = 0; seg < 3; ++seg) {       // nodes | adjB | glob
        #pragma unroll
        for (int ss = 0; ss < 4; ++ss) {
            const int off = ss * 32 + fg * 8;
            short8 a0, a1;
            if (seg == 1) {
                a0 = *(const short8*)(pa0 + off);
                a1 = *(const short8*)(pa1 + off);
            } else {
                const float* p0 = (seg == 0) ? pn0 : pg0;
                const float* p1 = (seg == 0) ? pn1 : pg1;
                const float4 x0 = *(const float4*)(p0 + off);
                const float4 y0 = *(const float4*)(p0 + off + 4);
                const float4 x1 = *(const float4*)(p1 + off);
                const float4 y1 = *(const float4*)(p1 + off + 4);
                a0 = pack8(x0, y0);
                a1 = pack8(x1, y1);
            }
            const u16* bp = bbp + (seg * 4 + ss) * 32;
            #pragma unroll
            for (int nt = 0; nt < 8; ++nt) {
                const short8 b = *(const short8*)(bp + nt * 6144);
                acc0[nt] = __builtin_amdgcn_mfma_f32_16x16x32_bf16(a0, b, acc0[nt], 0, 0, 0);
                acc1[nt] = __builtin_amdgcn_mfma_f32_16x16x32_bf16(a1, b, acc1[nt], 0, 0, 0);
            }
        }
    }

    float* ob = out + OFF_NODES;
    #pragma unroll
    for (int nt = 0; nt < 8; ++nt) {
        const int c = nt * 16 + fr;
        #pragma unroll
        for (int r = 0; r < 4; ++r) {
            const long rr = row0 + fg * 4 + r;
            ob[rr * DD + c] = fmaxf(acc0[nt][r] + bias[nt], 0.f);
            ob[(rr + 16) * DD + c] = fmaxf(acc1[nt][r] + bias[nt], 0.f);
        }
    }
}

// -------- agg + residual: one block per (b,g); no float atomics --------
__global__ __launch_bounds__(256) void agg_scan(
    const float* __restrict__ edges_in, const float* __restrict__ nodes_in,
    const int* __restrict__ egi, const int* __restrict__ ngi,
    const float* __restrict__ w_res,
    float* __restrict__ out, float* __restrict__ eagg, float* __restrict__ nagg) {
    __shared__ int idxl[256];
    __shared__ int lst[256];
    __shared__ int cntm;
    __shared__ float accl[256];
    const int tid = threadIdx.x;
    const int col = tid & 127, sub = tid >> 7;
    const float wr = w_res[0];
    float acc = 0.f;

    if (blockIdx.x < 512) {
        const int b = blockIdx.x >> 6, g = blockIdx.x & 63;
        const int* gi = egi + b * E_;
        const float* uRow = out + OFF_EDGES + (long)b * E_ * DD;
        const float* inRow = edges_in + (long)b * E_ * DD;
        float* oRow = out + OFF_EDGES + (long)b * E_ * DD;
        for (int c0 = 0; c0 < E_; c0 += 256) {
            if (tid == 0) cntm = 0;
            idxl[tid] = gi[c0 + tid];
            __syncthreads();
            if (idxl[tid] == g) { const int p = atomicAdd(&cntm, 1); lst[p] = tid; }
            __syncthreads();
            const int m = cntm;
            for (int j = sub; j < m; j += 2) {
                const long re = (long)(c0 + lst[j]) * DD + col;
                const float v = uRow[re];
                acc += v;
                oRow[re] = inRow[re] + wr * v;
            }
            __syncthreads();
        }
        accl[tid] = acc;
        __syncthreads();
        if (tid < 128)
            eagg[((long)b * G_ + g) * DD + tid] = accl[tid] + accl[tid + 128];
    } else {
        const int gid = blockIdx.x - 512;
        const int b = gid >> 6, g = gid & 63;
        const int* gi = ngi + b * N_;
        const float* uRow = out + OFF_NODES + (long)b * N_ * DD;
        const float* inRow = nodes_in + (long)b * N_ * DD;
        float* oRow = out + OFF_NODES + (long)b * N_ * DD;
        for (int c0 = 0; c0 < N_; c0 += 256) {
            if (tid == 0) cntm = 0;
            idxl[tid] = gi[c0 + tid];
            __syncthreads();
            if (idxl[tid] == g) { const int p = atomicAdd(&cntm, 1); lst[p] = tid; }
            __syncthreads();
            const int m = cntm;
            for (int j = sub; j < m; j += 2) {
                const long re = (long)(c0 + lst[j]) * DD + col;
                const float v = uRow[re];
                acc += v;
                oRow[re] = inRow[re] + wr * v;
            }
            __syncthreads();
        }
        accl[tid] = acc;
        __syncthreads();
        if (tid < 128)
            nagg[((long)b * G_ + g) * DD + tid] = accl[tid] + accl[tid + 128];
    }
}

// ---------------- global block: 512 rows, K=384, fp32 VALU ----------------
__global__ __launch_bounds__(128) void global_block(
    const float* __restrict__ nagg, const float* __restrict__ eagg,
    const float* __restrict__ glob,
    const float* __restrict__ Wg, const float* __restrict__ bg,
    const float* __restrict__ w_res, float* __restrict__ out) {
    __shared__ float gin[384];
    const int row = blockIdx.x;
    const int tid = threadIdx.x;
    gin[tid]       = nagg[row * DD + tid];
    gin[128 + tid] = eagg[row * DD + tid];
    gin[256 + tid] = glob[row * DD + tid];
    __syncthreads();
    float acc = bg[tid];
    #pragma unroll 4
    for (int k = 0; k < 384; ++k) acc += gin[k] * Wg[k * DD + tid];
    const float upd = fmaxf(acc, 0.f);
    out[OFF_GLOB + row * DD + tid] = glob[row * DD + tid] + w_res[0] * upd;
}

extern "C" void kernel_launch(void* const* d_in, const int* in_sizes, int n_in,
                              void* d_out, int out_size, void* d_ws, size_t ws_size,
                              hipStream_t stream) {
    const float* nodes     = (const float*)d_in[0];
    const float* edges     = (const float*)d_in[1];
    const int*   receivers = (const int*)d_in[2];
    const int*   senders   = (const int*)d_in[3];
    const float* glob      = (const float*)d_in[4];
    const int*   ngi       = (const int*)d_in[5];
    const int*   egi       = (const int*)d_in[6];
    const float* We        = (const float*)d_in[7];
    const float* be        = (const float*)d_in[8];
    const float* Wn        = (const float*)d_in[9];
    const float* bn        = (const float*)d_in[10];
    const float* Wg        = (const float*)d_in[11];
    const float* bg        = (const float*)d_in[12];
    const float* w_res     = (const float*)d_in[13];
    float* out = (float*)d_out;
    float* ws  = (float*)d_ws;
    float* eagg = ws + WS_EAGG;
    float* nagg = ws + WS_NAGG;
    int* cnt   = (int*)(ws + WS_CNT);
    int* rs    = (int*)(ws + WS_RS);
    int* cur   = (int*)(ws + WS_CUR);
    int* elist = (int*)(ws + WS_ELIST);
    u16* adjB  = (u16*)(ws + WS_ADJB);
    u16* WeT   = (u16*)(ws + WS_WET);
    u16* WnT   = (u16*)(ws + WS_WNT);

    hipLaunchKernelGGL(prep_w, dim3(448), dim3(256), 0, stream, We, Wn, WeT, WnT);
    hipLaunchKernelGGL(zero_cnt, dim3(32), dim3(256), 0, stream, (int4*)cnt);
    hipLaunchKernelGGL(copy_idx, dim3(512), dim3(256), 0, stream,
                       receivers, senders, ngi, egi, out);
    hipLaunchKernelGGL(k_hist, dim3(512), dim3(256), 0, stream, receivers, cnt);
    hipLaunchKernelGGL(k_scan, dim3(8), dim3(1024), 0, stream, cnt, rs, cur);
    hipLaunchKernelGGL(k_fill, dim3(512), dim3(256), 0, stream, receivers, cur, elist);
    hipLaunchKernelGGL(edge_mfma, dim3(BE_ / 128), dim3(256), 0, stream,
                       nodes, edges, receivers, senders, glob, egi, WeT, be, out);
    hipLaunchKernelGGL(adj_gather, dim3(BN_ / 64), dim3(256), 0, stream,
                       rs, cnt, elist, out + OFF_EDGES, adjB);
    hipLaunchKernelGGL(node_mfma, dim3(BN_ / 128), dim3(256), 0, stream,
                       nodes, adjB, glob, ngi, WnT, bn, out);
    hipLaunchKernelGGL(agg_scan, dim3(1024), dim3(256), 0, stream,
                       edges, nodes, egi, ngi, w_res, out, eagg, nagg);
    hipLaunchKernelGGL(global_block, dim3(BG_), dim3(128), 0, stream,
                       nagg, eagg, glob, Wg, bg, w_res, out);
}